// Round 11
// baseline (520.484 us; speedup 1.0000x reference)
//
#include <hip/hip_runtime.h>

// BinaryLinear: out = (x @ sign(w)^T) * alpha[o],  alpha = mean(|w|, axis=1)
// x: [65536,1024] f32, w: [1024,1024] f32, out: [65536,1024] f32
//
// R11: NO-LDS GEMM. The sign matrix is 2MB fp16; a block's per-K-tile B
//      working set is 16KB -> L1-resident. Both A and B are loaded directly
//      global->register in lane-exact MFMA fragment layout with PLAIN
//      compiler-tracked loads (the untracked-ALOAD family R6/R8/R10 is
//      abandoned after 3 aborts). Zero barriers, zero inline asm, waves fully
//      independent; A prefetched 1 K-tile ahead into a second named reg set.
//      128x256 block tile, 256 thr / 4 waves (2Mx2N), 64x128 per wave,
//      grid 2048 XCD-chunk-swizzled. launch_bounds(256,2).

typedef _Float16 half8 __attribute__((ext_vector_type(8)));
typedef _Float16 half4v __attribute__((ext_vector_type(4)));
typedef float f32x4 __attribute__((ext_vector_type(4)));

#define TOKENS 65536
#define INF 1024
#define OUTF 1024
#define BM 128
#define BN 256
#define NKT 32

__device__ __forceinline__ half8 cvt8(f32x4 a, f32x4 b) {
  half8 h;
  h[0] = (_Float16)a[0]; h[1] = (_Float16)a[1];
  h[2] = (_Float16)a[2]; h[3] = (_Float16)a[3];
  h[4] = (_Float16)b[0]; h[5] = (_Float16)b[1];
  h[6] = (_Float16)b[2]; h[7] = (_Float16)b[3];
  return h;
}

// ---------------- prep: alpha + sign(fp16) ----------------
__global__ __launch_bounds__(256) void bl_prep(const float* __restrict__ w,
                                               _Float16* __restrict__ sbin,
                                               float* __restrict__ alpha) {
  const int o = blockIdx.x;
  const int tid = threadIdx.x;
  const float4 v = ((const float4*)(w + (size_t)o * INF))[tid];
  float s = fabsf(v.x) + fabsf(v.y) + fabsf(v.z) + fabsf(v.w);
  half4v h;
  h[0] = (_Float16)((v.x > 0.f) ? 1.f : ((v.x < 0.f) ? -1.f : 0.f));
  h[1] = (_Float16)((v.y > 0.f) ? 1.f : ((v.y < 0.f) ? -1.f : 0.f));
  h[2] = (_Float16)((v.z > 0.f) ? 1.f : ((v.z < 0.f) ? -1.f : 0.f));
  h[3] = (_Float16)((v.w > 0.f) ? 1.f : ((v.w < 0.f) ? -1.f : 0.f));
  *(half4v*)(sbin + (size_t)o * INF + tid * 4) = h;
#pragma unroll
  for (int off = 32; off > 0; off >>= 1) s += __shfl_down(s, off, 64);
  __shared__ float red[4];
  const int wave = tid >> 6, lane = tid & 63;
  if (lane == 0) red[wave] = s;
  __syncthreads();
  if (tid == 0) alpha[o] = (red[0] + red[1] + red[2] + red[3]) * (1.0f / 1024.0f);
}

// ---------------- GEMM (no LDS, no barriers) ----------------
__global__ __launch_bounds__(256, 2) void bl_gemm(const float* __restrict__ x,
                                                  const _Float16* __restrict__ sbin,
                                                  const float* __restrict__ alpha,
                                                  float* __restrict__ out) {
  const int tid = threadIdx.x;
  const int lane = tid & 63;
  const int wid = tid >> 6; // 0..3
  const int l15 = lane & 15;
  const int kc = lane >> 4; // 0..3
  const int wr = wid >> 1;  // 0..1 (64-row slice)
  const int wc = wid & 1;   // 0..1 (128-col slice)

  // XCD chunked swizzle: 2048 blocks -> 256 consecutive per XCD;
  // 4 consecutive wgids share one A row-panel (L2 locality).
  const int bid = blockIdx.x;
  const int wgid = (bid & 7) * 256 + (bid >> 3);
  const int bm0 = (wgid >> 2) * BM; // 0..65408
  const int bn0 = (wgid & 3) * BN;  // 0..768

  // per-lane fragment bases, lane-exact MFMA layout:
  //   A: lane holds A[row=l15][k=kc*8+j]  -> x[bm0+wr*64+mf*16+l15][T*32+kc*8]
  //   B: lane holds B[col=l15][k=kc*8+j]  -> sbin[bn0+wc*128+nf*16+l15][T*32+kc*8]
  const float* aBase = x + (size_t)(bm0 + wr * 64 + l15) * INF + kc * 8;
  const _Float16* bBase = sbin + (size_t)(bn0 + wc * 128 + l15) * INF + kc * 8;

  f32x4 acc[4][8] = {};
  f32x4 a0[4][2], a1[4][2]; // named A reg sets (static indexing, rule 20)

#define LOADA(dst_, T_)                                                        \
  {                                                                            \
    _Pragma("unroll") for (int mf = 0; mf < 4; ++mf) {                         \
      dst_[mf][0] = *(const f32x4*)(aBase + mf * 16384 + (T_) * 32);           \
      dst_[mf][1] = *(const f32x4*)(aBase + mf * 16384 + (T_) * 32 + 4);       \
    }                                                                          \
  }

#define COMPUTE(areg_, T_)                                                     \
  {                                                                            \
    half8 af0 = cvt8(areg_[0][0], areg_[0][1]);                                \
    half8 af1 = cvt8(areg_[1][0], areg_[1][1]);                                \
    half8 af2 = cvt8(areg_[2][0], areg_[2][1]);                                \
    half8 af3 = cvt8(areg_[3][0], areg_[3][1]);                                \
    _Pragma("unroll") for (int nf = 0; nf < 8; ++nf) {                         \
      const half8 b = *(const half8*)(bBase + nf * 16384 + (T_) * 32);         \
      acc[0][nf] = __builtin_amdgcn_mfma_f32_16x16x32_f16(af0, b, acc[0][nf], 0, 0, 0); \
      acc[1][nf] = __builtin_amdgcn_mfma_f32_16x16x32_f16(af1, b, acc[1][nf], 0, 0, 0); \
      acc[2][nf] = __builtin_amdgcn_mfma_f32_16x16x32_f16(af2, b, acc[2][nf], 0, 0, 0); \
      acc[3][nf] = __builtin_amdgcn_mfma_f32_16x16x32_f16(af3, b, acc[3][nf], 0, 0, 0); \
    }                                                                          \
  }

  // prologue: A(0) in flight
  LOADA(a0, 0);

#pragma unroll 1
  for (int u = 0; u < NKT / 2; ++u) {
    const int Te = 2 * u;
    LOADA(a1, Te + 1);   // prefetch odd tile
    COMPUTE(a0, Te);     // compute even tile
    if (u + 1 < NKT / 2) // prefetch next even tile (uniform branch)
      LOADA(a0, Te + 2);
    COMPUTE(a1, Te + 1); // compute odd tile
  }
#undef COMPUTE
#undef LOADA

  // ---------------- epilogue: scale by alpha[col], store f32 ----------------
  float al[8];
#pragma unroll
  for (int n = 0; n < 8; ++n) al[n] = alpha[bn0 + wc * 128 + n * 16 + l15];
#pragma unroll
  for (int mf = 0; mf < 4; ++mf) {
    const int row0 = bm0 + wr * 64 + mf * 16 + kc * 4;
#pragma unroll
    for (int n = 0; n < 8; ++n) {
      const int col = bn0 + wc * 128 + n * 16 + l15;
#pragma unroll
      for (int j = 0; j < 4; ++j)
        out[(size_t)(row0 + j) * OUTF + col] = acc[mf][n][j] * al[n];
    }
  }
}

extern "C" void kernel_launch(void* const* d_in, const int* in_sizes, int n_in,
                              void* d_out, int out_size, void* d_ws, size_t ws_size,
                              hipStream_t stream) {
  const float* x = (const float*)d_in[0];
  const float* w = (const float*)d_in[1];
  float* out = (float*)d_out;
  _Float16* sbin = (_Float16*)d_ws;                              // 2 MB
  float* alpha = (float*)((char*)d_ws + (size_t)OUTF * INF * 2); // 4 KB

  bl_prep<<<dim3(OUTF), dim3(256), 0, stream>>>(w, sbin, alpha);
  bl_gemm<<<dim3((TOKENS / BM) * (OUTF / BN)), dim3(256), 0, stream>>>(x, sbin, alpha, out);
}

// Round 12
// 229.185 us; speedup vs baseline: 2.2710x; 2.2710x over previous
//
#include <hip/hip_runtime.h>

// BinaryLinear: out = (x @ sign(w)^T) * alpha[o],  alpha = mean(|w|, axis=1)
// x: [65536,1024] f32, w: [1024,1024] f32, out: [65536,1024] f32
//
// R12: both operands DMA-staged (global_load_lds), A kept f32 in LDS and
//      converted to fp16 at the read side (kills R5's serial ALOAD->cvt->
//      ds_write chain; no untracked-asm loads -> no crash family).
//      256x256 tile, BK=32, 8 waves (4M x 2N, 64x128 each).
//      A: 3 x 32KB f32 buffers; B: 3 x 16KB fp16 buffers (144KB LDS).
//      Lead-2 staging, 6 DMA/thread/phase, gate vmcnt(6) + one raw s_barrier
//      per phase (m201 invariant: gate BEFORE barrier). XOR-swizzled LDS via
//      pre-swizzled DMA source (rule 21). setprio around MFMA cluster.

typedef _Float16 half8 __attribute__((ext_vector_type(8)));
typedef _Float16 half4v __attribute__((ext_vector_type(4)));
typedef float f32x4 __attribute__((ext_vector_type(4)));

#define TOKENS 65536
#define INF 1024
#define OUTF 1024
#define BM 256
#define BN 256
#define BK 32
#define NKT 32

__device__ __forceinline__ void gload_lds16(const void* g, void* l) {
  __builtin_amdgcn_global_load_lds(
      (const __attribute__((address_space(1))) unsigned int*)g,
      (__attribute__((address_space(3))) unsigned int*)l, 16, 0, 0);
}

__device__ __forceinline__ half8 cvt8(f32x4 a, f32x4 b) {
  half8 h;
  h[0] = (_Float16)a[0]; h[1] = (_Float16)a[1];
  h[2] = (_Float16)a[2]; h[3] = (_Float16)a[3];
  h[4] = (_Float16)b[0]; h[5] = (_Float16)b[1];
  h[6] = (_Float16)b[2]; h[7] = (_Float16)b[3];
  return h;
}

// ---------------- prep: alpha + sign(fp16) ----------------
__global__ __launch_bounds__(256) void bl_prep(const float* __restrict__ w,
                                               _Float16* __restrict__ sbin,
                                               float* __restrict__ alpha) {
  const int o = blockIdx.x;
  const int tid = threadIdx.x;
  const float4 v = ((const float4*)(w + (size_t)o * INF))[tid];
  float s = fabsf(v.x) + fabsf(v.y) + fabsf(v.z) + fabsf(v.w);
  half4v h;
  h[0] = (_Float16)((v.x > 0.f) ? 1.f : ((v.x < 0.f) ? -1.f : 0.f));
  h[1] = (_Float16)((v.y > 0.f) ? 1.f : ((v.y < 0.f) ? -1.f : 0.f));
  h[2] = (_Float16)((v.z > 0.f) ? 1.f : ((v.z < 0.f) ? -1.f : 0.f));
  h[3] = (_Float16)((v.w > 0.f) ? 1.f : ((v.w < 0.f) ? -1.f : 0.f));
  *(half4v*)(sbin + (size_t)o * INF + tid * 4) = h;
#pragma unroll
  for (int off = 32; off > 0; off >>= 1) s += __shfl_down(s, off, 64);
  __shared__ float red[4];
  const int wave = tid >> 6, lane = tid & 63;
  if (lane == 0) red[wave] = s;
  __syncthreads();
  if (tid == 0) alpha[o] = (red[0] + red[1] + red[2] + red[3]) * (1.0f / 1024.0f);
}

// ---------------- GEMM ----------------
__global__ __launch_bounds__(512, 2) void bl_gemm(const float* __restrict__ x,
                                                  const _Float16* __restrict__ sbin,
                                                  const float* __restrict__ alpha,
                                                  float* __restrict__ out) {
  __shared__ float ldsA[3][BM * BK];    // 3 x 32KB = 96KB (A as f32)
  __shared__ _Float16 ldsB[3][BN * BK]; // 3 x 16KB = 48KB

  const int tid = threadIdx.x;
  const int lane = tid & 63;
  const int wid = tid >> 6;
  const int l15 = lane & 15;
  const int kc = lane >> 4; // 0..3
  const int wr = wid >> 1;  // 0..3 (64-row slice)
  const int wc = wid & 1;   // 0..1 (128-col slice)

  // XCD chunked swizzle: 1024 blocks -> 128 consecutive per XCD;
  // 4 consecutive wgids share one A row-panel (L2 locality).
  const int bid = blockIdx.x;
  const int wgid = (bid & 7) * 128 + (bid >> 3);
  const int bm0 = (wgid >> 2) * BM;
  const int bn0 = (wgid & 3) * BN;

  // ---- A staging: 32KB tile = 2048 x 16B chunks; thread owns 4 ----
  // LDS[row][slot s] holds source chunk s ^ (row&7)  (8-slot involution)
  size_t aSrc[4];
  int aDst[4];
#pragma unroll
  for (int q = 0; q < 4; ++q) {
    const int ci = q * 512 + tid;
    const int row = ci >> 3;
    const int c = (ci & 7) ^ (row & 7);
    aSrc[q] = (size_t)(bm0 + row) * INF + c * 4; // f32 elems (pre-swizzled src)
    aDst[q] = ci * 16;                           // linear LDS byte dest
  }
  // ---- B staging: 16KB tile = 1024 x 16B chunks; thread owns 2 ----
  // LDS[row][slot s] holds source chunk s ^ (row&3)
  size_t bSrc[2];
  int bDst[2];
#pragma unroll
  for (int p = 0; p < 2; ++p) {
    const int ci = p * 512 + tid;
    const int row = ci >> 2;
    const int c = (ci & 3) ^ (row & 3);
    bSrc[p] = (size_t)(bn0 + row) * INF + c * 8; // fp16 elems (pre-swizzled src)
    bDst[p] = ci * 16;
  }
  // ---- fragment read offsets (bytes within a buffer) ----
  // A f32: frag mf needs source chunks 2kc, 2kc+1 of row wr*64+mf*16+l15
  int aRd[4][2];
#pragma unroll
  for (int mf = 0; mf < 4; ++mf) {
    const int row = wr * 64 + mf * 16 + l15;
#pragma unroll
    for (int d = 0; d < 2; ++d)
      aRd[mf][d] = row * 128 + (((2 * kc + d) ^ (row & 7)) << 4);
  }
  // B fp16: frag nf needs source chunk kc of row wc*128+nf*16+l15
  int bRd[8];
#pragma unroll
  for (int nf = 0; nf < 8; ++nf) {
    const int row = wc * 128 + nf * 16 + l15;
    bRd[nf] = row * 64 + ((kc ^ (row & 3)) << 4);
  }

  f32x4 acc[4][8] = {};

#define STAGE(SB_, tk_)                                                        \
  {                                                                            \
    const size_t ko_ = (size_t)(tk_) * BK;                                     \
    gload_lds16(x + aSrc[0] + ko_, (char*)&ldsA[SB_][0] + aDst[0]);            \
    gload_lds16(x + aSrc[1] + ko_, (char*)&ldsA[SB_][0] + aDst[1]);            \
    gload_lds16(x + aSrc[2] + ko_, (char*)&ldsA[SB_][0] + aDst[2]);            \
    gload_lds16(x + aSrc[3] + ko_, (char*)&ldsA[SB_][0] + aDst[3]);            \
    gload_lds16(sbin + bSrc[0] + ko_, (char*)&ldsB[SB_][0] + bDst[0]);         \
    gload_lds16(sbin + bSrc[1] + ko_, (char*)&ldsB[SB_][0] + bDst[1]);         \
  }

#define COMPUTE(RB_)                                                           \
  {                                                                            \
    const char* pa_ = (const char*)&ldsA[RB_][0];                              \
    const char* pb_ = (const char*)&ldsB[RB_][0];                              \
    f32x4 lo0 = *(const f32x4*)(pa_ + aRd[0][0]);                              \
    f32x4 hi0 = *(const f32x4*)(pa_ + aRd[0][1]);                              \
    f32x4 lo1 = *(const f32x4*)(pa_ + aRd[1][0]);                              \
    f32x4 hi1 = *(const f32x4*)(pa_ + aRd[1][1]);                              \
    f32x4 lo2 = *(const f32x4*)(pa_ + aRd[2][0]);                              \
    f32x4 hi2 = *(const f32x4*)(pa_ + aRd[2][1]);                              \
    f32x4 lo3 = *(const f32x4*)(pa_ + aRd[3][0]);                              \
    f32x4 hi3 = *(const f32x4*)(pa_ + aRd[3][1]);                              \
    const half8 af0 = cvt8(lo0, hi0);                                          \
    const half8 af1 = cvt8(lo1, hi1);                                          \
    const half8 af2 = cvt8(lo2, hi2);                                          \
    const half8 af3 = cvt8(lo3, hi3);                                          \
    __builtin_amdgcn_s_setprio(1);                                             \
    _Pragma("unroll") for (int nf = 0; nf < 8; ++nf) {                         \
      const half8 b = *(const half8*)(pb_ + bRd[nf]);                          \
      acc[0][nf] = __builtin_amdgcn_mfma_f32_16x16x32_f16(af0, b, acc[0][nf], 0, 0, 0); \
      acc[1][nf] = __builtin_amdgcn_mfma_f32_16x16x32_f16(af1, b, acc[1][nf], 0, 0, 0); \
      acc[2][nf] = __builtin_amdgcn_mfma_f32_16x16x32_f16(af2, b, acc[2][nf], 0, 0, 0); \
      acc[3][nf] = __builtin_amdgcn_mfma_f32_16x16x32_f16(af3, b, acc[3][nf], 0, 0, 0); \
    }                                                                          \
    __builtin_amdgcn_s_setprio(0);                                             \
  }

// Phase T: stage tile T+2 (issued right after previous barrier -> DMA overlaps
// this phase's compute), compute tile T, gate vmcnt(6) [retires tile T+1's 6
// DMAs; leaves tile T+2's 6 in flight], barrier -> T+1 visible to all waves.
#define PH(T_, RB_, SB_)                                                       \
  {                                                                            \
    STAGE(SB_, (T_) + 2);                                                      \
    COMPUTE(RB_);                                                              \
    asm volatile("s_waitcnt vmcnt(6)" ::: "memory");                           \
    __builtin_amdgcn_s_barrier();                                              \
  }

  // ---------------- prologue: stage tiles 0,1 ----------------
  STAGE(0, 0);
  STAGE(1, 1);
  asm volatile("s_waitcnt vmcnt(6)" ::: "memory"); // tile 0 resident
  __builtin_amdgcn_s_barrier();

#pragma unroll 1
  for (int u = 0; u < 10; ++u) { // phases 0..29, static buffer roles
    PH(3 * u + 0, 0, 2)
    PH(3 * u + 1, 1, 0)
    PH(3 * u + 2, 2, 1)
  }
  // phase 30: compute tile 30 (buf 0); retire tile 31; barrier
  COMPUTE(0);
  asm volatile("s_waitcnt vmcnt(0)" ::: "memory");
  __builtin_amdgcn_s_barrier();
  // phase 31: compute tile 31 (buf 1)
  COMPUTE(1);

#undef PH
#undef COMPUTE
#undef STAGE

  // ---------------- epilogue: scale by alpha[col], store f32 ----------------
  float al[8];
#pragma unroll
  for (int n = 0; n < 8; ++n) al[n] = alpha[bn0 + wc * 128 + n * 16 + l15];
#pragma unroll
  for (int mf = 0; mf < 4; ++mf) {
    const int row0 = bm0 + wr * 64 + mf * 16 + kc * 4;
#pragma unroll
    for (int n = 0; n < 8; ++n) {
      const int col = bn0 + wc * 128 + n * 16 + l15;
#pragma unroll
      for (int j = 0; j < 4; ++j)
        out[(size_t)(row0 + j) * OUTF + col] = acc[mf][n][j] * al[n];
    }
  }
}

extern "C" void kernel_launch(void* const* d_in, const int* in_sizes, int n_in,
                              void* d_out, int out_size, void* d_ws, size_t ws_size,
                              hipStream_t stream) {
  const float* x = (const float*)d_in[0];
  const float* w = (const float*)d_in[1];
  float* out = (float*)d_out;
  _Float16* sbin = (_Float16*)d_ws;                              // 2 MB
  float* alpha = (float*)((char*)d_ws + (size_t)OUTF * INF * 2); // 4 KB

  bl_prep<<<dim3(OUTF), dim3(256), 0, stream>>>(w, sbin, alpha);
  bl_gemm<<<dim3((TOKENS / BM) * (OUTF / BN)), dim3(512), 0, stream>>>(x, sbin, alpha, out);
}